// Round 1
// baseline (3971.337 us; speedup 1.0000x reference)
//
#include <hip/hip_runtime.h>
#include <math.h>

#define T_SEQ  1024
#define C_DIM  1024
#define NH_    16
#define H_DIM  64

// ---------------------------------------------------------------------------
// Complex GEMM: Y[m][n] = sum_k X[m][k] * W[n][k]  + bias[n]   (complex)
// X: [M=2048, C_DIM] complex interleaved; W: [C_DIM, C_DIM] complex; bias: [C_DIM] complex
// MODE 0: plain [M, C_DIM] complex out (final projection, writes d_out)
// MODE 1: head-split [B,H,T,D] out + RoPE (q, k)
// MODE 2: head-split out, no RoPE (v)
// ---------------------------------------------------------------------------
template<int MODE>
__global__ __launch_bounds__(256)
void cgemm_kernel(const float* __restrict__ X, const float* __restrict__ W,
                  const float* __restrict__ bias, float* __restrict__ Y)
{
    __shared__ float Xsr[64*17], Xsi[64*17], Wsr[64*17], Wsi[64*17];
    const int t  = threadIdx.x;
    const int tx = t & 15, ty = t >> 4;
    const int n0 = blockIdx.x * 64, m0 = blockIdx.y * 64;
    const int ty4 = ty * 4, tx4 = tx * 4;

    float cr[4][4] = {{0.f}}, ci[4][4] = {{0.f}};

    for (int k0 = 0; k0 < C_DIM; k0 += 16) {
#pragma unroll
        for (int l = 0; l < 4; l++) {
            int idx = t + 256 * l;          // 1024 float2 per matrix
            int row = idx >> 4, kk = idx & 15;
            float2 xv = *(const float2*)(X + ((size_t)(m0 + row) * C_DIM + k0 + kk) * 2);
            Xsr[row*17 + kk] = xv.x; Xsi[row*17 + kk] = xv.y;
            float2 wv = *(const float2*)(W + ((size_t)(n0 + row) * C_DIM + k0 + kk) * 2);
            Wsr[row*17 + kk] = wv.x; Wsi[row*17 + kk] = wv.y;
        }
        __syncthreads();
#pragma unroll
        for (int k = 0; k < 16; k++) {
            float ar[4], ai[4], br[4], bi[4];
#pragma unroll
            for (int i = 0; i < 4; i++) { ar[i] = Xsr[(ty4+i)*17 + k]; ai[i] = Xsi[(ty4+i)*17 + k]; }
#pragma unroll
            for (int j = 0; j < 4; j++) { br[j] = Wsr[(tx4+j)*17 + k]; bi[j] = Wsi[(tx4+j)*17 + k]; }
#pragma unroll
            for (int i = 0; i < 4; i++)
#pragma unroll
                for (int j = 0; j < 4; j++) {
                    cr[i][j] += ar[i]*br[j] - ai[i]*bi[j];
                    ci[i][j] += ar[i]*bi[j] + ai[i]*br[j];
                }
        }
        __syncthreads();
    }

#pragma unroll
    for (int i = 0; i < 4; i++) {
        int m = m0 + ty4 + i;
#pragma unroll
        for (int j = 0; j < 4; j++) {
            int n = n0 + tx4 + j;
            float yr = cr[i][j] + bias[2*n];
            float yi = ci[i][j] + bias[2*n + 1];
            if (MODE == 0) {
                *(float2*)(Y + ((size_t)m * C_DIM + n) * 2) = make_float2(yr, yi);
            } else {
                if (MODE == 1) {
                    int tpos = m & (T_SEQ - 1);
                    int d    = n & (H_DIM - 1);
                    // inv_freq = 10000^(-d/64) ; log2(10000)/64 = 0.2076205059304601
                    float invf = exp2f((float)d * -0.2076205059304601f);
                    float fr   = (float)tpos * invf;
                    float sn, cs;
                    sincosf(fr, &sn, &cs);
                    float r2 = yr*cs - yi*sn;
                    float i2 = yr*sn + yi*cs;
                    yr = r2; yi = i2;
                }
                // [B,H,T,D] complex
                size_t oidx = ((((size_t)(m >> 10) * NH_ + (n >> 6)) * T_SEQ
                                + (m & (T_SEQ - 1))) * H_DIM + (n & (H_DIM - 1))) * 2;
                *(float2*)(Y + oidx) = make_float2(yr, yi);
            }
        }
    }
}

// ---------------------------------------------------------------------------
// Flash-style complex attention for one (b, h, 16-row Q tile).
// q,k,v: [B,H,T,2*D] floats (complex interleaved). out: [B,T,C,2] floats.
// score = |q . conj(k)| / 8 ; softmax over s ; O = P @ v (P real).
// ---------------------------------------------------------------------------
__global__ __launch_bounds__(256)
void attn_kernel(const float* __restrict__ q, const float* __restrict__ k,
                 const float* __restrict__ v, float* __restrict__ out)
{
    __shared__ float Qs[16*132];
    __shared__ float Ks[32*132];
    __shared__ float Vs[32*132];
    __shared__ float S [16*33];
    __shared__ float mrow[16], lrow[16], arow[16];

    const int t  = threadIdx.x;
    const int q0 = blockIdx.x * 16;
    const int h  = blockIdx.y, b = blockIdx.z;
    const size_t headbase = ((size_t)(b * NH_ + h) * T_SEQ) * (2 * H_DIM);

    // Q tile: 16 rows x 128 floats = 512 float4
    {
        const float* qp = q + headbase + (size_t)q0 * 128;
#pragma unroll
        for (int l = 0; l < 2; l++) {
            int idx = t + 256 * l;
            int row = idx >> 5, w = idx & 31;
            *(float4*)(&Qs[row*132 + w*4]) = *(const float4*)(qp + row*128 + w*4);
        }
        if (t < 16) { mrow[t] = -INFINITY; lrow[t] = 0.f; }
    }

    float4 O0 = make_float4(0.f,0.f,0.f,0.f);
    float4 O1 = make_float4(0.f,0.f,0.f,0.f);
    const int orow = t >> 4, oc = t & 15;        // O-update mapping
    const int sr = t & 15, ss = t >> 4;          // score mapping: (sr, ss) & (sr, ss+16)

    for (int it = 0; it < 32; it++) {
        const int s0 = it * 32;
        __syncthreads();   // previous iteration's S/Vs consumers done
        // K,V tile: 32 rows x 128 floats each = 1024 float4 each
        const float* kp = k + headbase + (size_t)s0 * 128;
        const float* vp = v + headbase + (size_t)s0 * 128;
#pragma unroll
        for (int l = 0; l < 4; l++) {
            int idx = t + 256 * l;
            int row = idx >> 5, w = idx & 31;
            *(float4*)(&Ks[row*132 + w*4]) = *(const float4*)(kp + row*128 + w*4);
            *(float4*)(&Vs[row*132 + w*4]) = *(const float4*)(vp + row*128 + w*4);
        }
        __syncthreads();

        // scores: 2 per thread, same Q row
        {
            float re0 = 0.f, im0 = 0.f, re1 = 0.f, im1 = 0.f;
#pragma unroll
            for (int d = 0; d < 64; d++) {
                float2 qv = *(const float2*)(&Qs[sr*132 + 2*d]);
                float2 ka = *(const float2*)(&Ks[ss*132 + 2*d]);
                float2 kb = *(const float2*)(&Ks[(ss+16)*132 + 2*d]);
                re0 += qv.x*ka.x + qv.y*ka.y;
                im0 += qv.y*ka.x - qv.x*ka.y;
                re1 += qv.x*kb.x + qv.y*kb.y;
                im1 += qv.y*kb.x - qv.x*kb.y;
            }
            S[sr*33 + ss]      = sqrtf(re0*re0 + im0*im0) * 0.125f;
            S[sr*33 + ss + 16] = sqrtf(re1*re1 + im1*im1) * 0.125f;
        }
        __syncthreads();

        // online softmax (one thread per Q row)
        if (t < 16) {
            int r = t;
            float mold = mrow[r], mnew = mold;
            for (int s = 0; s < 32; s++) mnew = fmaxf(mnew, S[r*33 + s]);
            float al = expf(mold - mnew);
            float l2 = lrow[r] * al;
            for (int s = 0; s < 32; s++) {
                float p = expf(S[r*33 + s] - mnew);
                S[r*33 + s] = p;
                l2 += p;
            }
            mrow[r] = mnew; lrow[r] = l2; arow[r] = al;
        }
        __syncthreads();

        // O update: thread covers comps oc*4..oc*4+3 and +64 of row orow
        {
            float al = arow[orow];
            O0.x *= al; O0.y *= al; O0.z *= al; O0.w *= al;
            O1.x *= al; O1.y *= al; O1.z *= al; O1.w *= al;
#pragma unroll 8
            for (int s = 0; s < 32; s++) {
                float p = S[orow*33 + s];
                float4 v0 = *(const float4*)(&Vs[s*132 + oc*4]);
                float4 v1 = *(const float4*)(&Vs[s*132 + 64 + oc*4]);
                O0.x += p*v0.x; O0.y += p*v0.y; O0.z += p*v0.z; O0.w += p*v0.w;
                O1.x += p*v1.x; O1.y += p*v1.y; O1.z += p*v1.z; O1.w += p*v1.w;
            }
        }
    }

    // epilogue: out[b, q0+orow, h*64 + d, part] ; comp index cc maps to h*128+cc
    {
        float inv = 1.f / lrow[orow];
        size_t rowbase = ((size_t)b * T_SEQ + q0 + orow) * (C_DIM * 2) + (size_t)h * 128;
        float4 a0 = make_float4(O0.x*inv, O0.y*inv, O0.z*inv, O0.w*inv);
        float4 a1 = make_float4(O1.x*inv, O1.y*inv, O1.z*inv, O1.w*inv);
        *(float4*)(&out[rowbase + oc*4])      = a0;
        *(float4*)(&out[rowbase + 64 + oc*4]) = a1;
    }
}

// ---------------------------------------------------------------------------
// Workspace layout (floats): q | k | v | attn_out, each B*H*T*D*2 = 4194304
// Total 64 MiB. All buffers fully overwritten every launch.
// ---------------------------------------------------------------------------
extern "C" void kernel_launch(void* const* d_in, const int* in_sizes, int n_in,
                              void* d_out, int out_size, void* d_ws, size_t ws_size,
                              hipStream_t stream) {
    const float* x  = (const float*)d_in[0];
    const float* wq = (const float*)d_in[1];
    const float* bq = (const float*)d_in[2];
    const float* wk = (const float*)d_in[3];
    const float* bk = (const float*)d_in[4];
    const float* wv = (const float*)d_in[5];
    const float* bv = (const float*)d_in[6];
    const float* wo = (const float*)d_in[7];
    const float* bo = (const float*)d_in[8];

    float* ws = (float*)d_ws;
    const size_t BUF = (size_t)2 * NH_ * T_SEQ * H_DIM * 2;  // 4194304
    float* qb = ws;
    float* kb = ws + BUF;
    float* vb = ws + 2*BUF;
    float* ab = ws + 3*BUF;
    float* outp = (float*)d_out;

    dim3 gb(C_DIM/64, 2*T_SEQ/64), tb(256);
    cgemm_kernel<1><<<gb, tb, 0, stream>>>(x,  wq, bq, qb);
    cgemm_kernel<1><<<gb, tb, 0, stream>>>(x,  wk, bk, kb);
    cgemm_kernel<2><<<gb, tb, 0, stream>>>(x,  wv, bv, vb);
    attn_kernel<<<dim3(T_SEQ/16, NH_, 2), tb, 0, stream>>>(qb, kb, vb, ab);
    cgemm_kernel<0><<<gb, tb, 0, stream>>>(ab, wo, bo, outp);
}

// Round 2
// 850.056 us; speedup vs baseline: 4.6719x; 4.6719x over previous
//
#include <hip/hip_runtime.h>
#include <math.h>

#define T_SEQ  1024
#define C_DIM  1024
#define NH_    16
#define H_DIM  64

typedef __bf16 bf16;
typedef __bf16 bf16x4 __attribute__((ext_vector_type(4)));
typedef __bf16 bf16x8 __attribute__((ext_vector_type(8)));
typedef float  f32x4  __attribute__((ext_vector_type(4)));

#define GLOAD_LDS16(g, l) __builtin_amdgcn_global_load_lds( \
    (const __attribute__((address_space(1))) void*)(g),     \
    (__attribute__((address_space(3))) void*)(l), 16, 0, 0)

__device__ __forceinline__ bf16x8 neg8(bf16x8 x) {
    union { bf16x8 v; unsigned int u[4]; } t;
    t.v = x;
    t.u[0] ^= 0x80008000u; t.u[1] ^= 0x80008000u;
    t.u[2] ^= 0x80008000u; t.u[3] ^= 0x80008000u;
    return t.v;
}

__device__ __forceinline__ float b2f(unsigned short u) {
    union { unsigned int x; float f; } t; t.x = (unsigned int)u << 16; return t.f;
}

// ---------------------------------------------------------------------------
// fp32 complex [R][1024][2] -> bf16 planes [R][1024] (re, im)
// ---------------------------------------------------------------------------
__global__ __launch_bounds__(256)
void split_complex(const float* __restrict__ in, bf16* __restrict__ pr,
                   bf16* __restrict__ pi) {
    int idx = (blockIdx.x * 256 + threadIdx.x) * 4;
    float4 v0 = *(const float4*)(in + (size_t)idx * 2);
    float4 v1 = *(const float4*)(in + (size_t)idx * 2 + 4);
    bf16x4 r, im;
    r[0] = (bf16)v0.x; r[1] = (bf16)v0.z; r[2] = (bf16)v1.x; r[3] = (bf16)v1.z;
    im[0] = (bf16)v0.y; im[1] = (bf16)v0.w; im[2] = (bf16)v1.y; im[3] = (bf16)v1.w;
    *(bf16x4*)(pr + idx) = r;
    *(bf16x4*)(pi + idx) = im;
}

// ---------------------------------------------------------------------------
// Complex GEMM core: Y[m][n] = sum_k A[m][k]*B[n][k] + bias[n]  (complex)
// A planes [M][1024], B planes [N][1024] bf16. Tile 128(M) x 64(N), BK=32.
// MODE 0: fp32 interleaved [m][1024][2] out.  MODE 1: bf16 head-split
// [B,H,T,128] out, optional RoPE.
// ---------------------------------------------------------------------------
template<int MODE>
__device__ __forceinline__ void cgemm_core(
    const bf16* __restrict__ Ar, const bf16* __restrict__ Ai,
    const bf16* __restrict__ Br, const bf16* __restrict__ Bi,
    const float* __restrict__ bias, void* __restrict__ Yv,
    int m0, int n0, bool rope)
{
    __shared__ __attribute__((aligned(16))) bf16 Asr[128 * 32];
    __shared__ __attribute__((aligned(16))) bf16 Asi[128 * 32];
    __shared__ __attribute__((aligned(16))) bf16 Bsr[64 * 32];
    __shared__ __attribute__((aligned(16))) bf16 Bsi[64 * 32];

    const int t = threadIdx.x, lane = t & 63, wave = t >> 6;
    const int wm = (wave >> 1) * 64, wn = (wave & 1) * 32;
    const int lm = lane & 15, quad = lane >> 4;
    const int lr = lane >> 2, lk = (lane & 3) * 8;   // staging row / k-offset

    f32x4 accr[4][2], acci[4][2];
#pragma unroll
    for (int i = 0; i < 4; i++)
#pragma unroll
        for (int j = 0; j < 2; j++) {
            accr[i][j] = (f32x4)0.f; acci[i][j] = (f32x4)0.f;
        }

    for (int k0 = 0; k0 < C_DIM; k0 += 32) {
#pragma unroll
        for (int j = 0; j < 6; j++) {
            int c = wave + 4 * j;
            const bf16* src; bf16* dst;
            if (c < 8)       { src = Ar + (size_t)(m0 + c * 16 + lr) * C_DIM + k0 + lk;        dst = Asr + c * 512; }
            else if (c < 16) { int cc = c - 8;  src = Ai + (size_t)(m0 + cc * 16 + lr) * C_DIM + k0 + lk; dst = Asi + cc * 512; }
            else if (c < 20) { int cc = c - 16; src = Br + (size_t)(n0 + cc * 16 + lr) * C_DIM + k0 + lk; dst = Bsr + cc * 512; }
            else             { int cc = c - 20; src = Bi + (size_t)(n0 + cc * 16 + lr) * C_DIM + k0 + lk; dst = Bsi + cc * 512; }
            GLOAD_LDS16(src, dst);
        }
        __syncthreads();

        bf16x8 ar[4], ai_[4], br_[2], bi_[2], bn_[2];
#pragma unroll
        for (int i = 0; i < 4; i++) {
            int off = (wm + i * 16 + lm) * 32 + quad * 8;
            ar[i]  = *(const bf16x8*)&Asr[off];
            ai_[i] = *(const bf16x8*)&Asi[off];
        }
#pragma unroll
        for (int j = 0; j < 2; j++) {
            int off = (wn + j * 16 + lm) * 32 + quad * 8;
            br_[j] = *(const bf16x8*)&Bsr[off];
            bi_[j] = *(const bf16x8*)&Bsi[off];
            bn_[j] = neg8(bi_[j]);
        }
#pragma unroll
        for (int i = 0; i < 4; i++)
#pragma unroll
            for (int j = 0; j < 2; j++) {
                accr[i][j] = __builtin_amdgcn_mfma_f32_16x16x32_bf16(ar[i],  br_[j], accr[i][j], 0, 0, 0);
                accr[i][j] = __builtin_amdgcn_mfma_f32_16x16x32_bf16(ai_[i], bn_[j], accr[i][j], 0, 0, 0);
                acci[i][j] = __builtin_amdgcn_mfma_f32_16x16x32_bf16(ar[i],  bi_[j], acci[i][j], 0, 0, 0);
                acci[i][j] = __builtin_amdgcn_mfma_f32_16x16x32_bf16(ai_[i], br_[j], acci[i][j], 0, 0, 0);
            }
        __syncthreads();
    }

    // epilogue — C/D layout: col = lane&15, row = quad*4 + reg
#pragma unroll
    for (int i = 0; i < 4; i++) {
#pragma unroll
        for (int j = 0; j < 2; j++) {
            int n = n0 + wn + j * 16 + lm;
            float2 bv = *(const float2*)&bias[2 * n];
#pragma unroll
            for (int r = 0; r < 4; r++) {
                int m = m0 + wm + i * 16 + quad * 4 + r;
                float yr = accr[i][j][r] + bv.x;
                float yi = acci[i][j][r] + bv.y;
                if (MODE == 0) {
                    float* Y = (float*)Yv;
                    *(float2*)&Y[((size_t)m * C_DIM + n) * 2] = make_float2(yr, yi);
                } else {
                    int tpos = m & (T_SEQ - 1), bb = m >> 10;
                    int h = n >> 6, d = n & (H_DIM - 1);
                    if (rope) {
                        float invf = exp2f((float)d * -0.2076205059304601f);
                        float fr = (float)tpos * invf;
                        float sn, cs; sincosf(fr, &sn, &cs);
                        float r2 = yr * cs - yi * sn;
                        float i2 = yr * sn + yi * cs;
                        yr = r2; yi = i2;
                    }
                    bf16* Y = (bf16*)Yv;
                    size_t o = (((size_t)(bb * NH_ + h) * T_SEQ + tpos) * 2 * H_DIM + d * 2);
                    union { bf16 b[2]; unsigned int u; } p;
                    p.b[0] = (bf16)yr; p.b[1] = (bf16)yi;
                    *(unsigned int*)&Y[o] = p.u;
                }
            }
        }
    }
}

__global__ __launch_bounds__(256, 2)
void qkv_gemm(const bf16* __restrict__ Xr, const bf16* __restrict__ Xi,
              const bf16* __restrict__ Wqr, const bf16* __restrict__ Wqi,
              const bf16* __restrict__ Wkr, const bf16* __restrict__ Wki,
              const bf16* __restrict__ Wvr, const bf16* __restrict__ Wvi,
              const float* __restrict__ bq, const float* __restrict__ bk,
              const float* __restrict__ bv,
              bf16* __restrict__ qo, bf16* __restrict__ ko, bf16* __restrict__ vo)
{
    const bf16 *Br, *Bi; const float* bias; bf16* Y;
    if (blockIdx.z == 0)      { Br = Wqr; Bi = Wqi; bias = bq; Y = qo; }
    else if (blockIdx.z == 1) { Br = Wkr; Bi = Wki; bias = bk; Y = ko; }
    else                      { Br = Wvr; Bi = Wvi; bias = bv; Y = vo; }
    cgemm_core<1>(Xr, Xi, Br, Bi, bias, Y, blockIdx.y * 128, blockIdx.x * 64,
                  blockIdx.z < 2);
}

__global__ __launch_bounds__(256, 2)
void out_gemm(const bf16* __restrict__ Ar, const bf16* __restrict__ Ai,
              const bf16* __restrict__ Br, const bf16* __restrict__ Bi,
              const float* __restrict__ bias, float* __restrict__ Y)
{
    cgemm_core<0>(Ar, Ai, Br, Bi, bias, Y, blockIdx.y * 128, blockIdx.x * 64, false);
}

// ---------------------------------------------------------------------------
// Flash-style complex attention (fp32 compute, bf16 I/O).
// q,k,v: bf16 [B,H,T,128] interleaved complex. Output: bf16 planes
// ABr/ABi [B*T][1024] (re/im of attn output, head-merged) for the out-proj.
// ---------------------------------------------------------------------------
__global__ __launch_bounds__(256)
void attn_kernel(const unsigned short* __restrict__ q,
                 const unsigned short* __restrict__ k,
                 const unsigned short* __restrict__ v,
                 bf16* __restrict__ ABr, bf16* __restrict__ ABi)
{
    __shared__ float Qs[16 * 132];
    __shared__ float Ks[32 * 132];
    __shared__ float Vs[32 * 132];
    __shared__ float S [16 * 33];
    __shared__ float mrow[16], lrow[16], arow[16];

    const int t  = threadIdx.x;
    const int q0 = blockIdx.x * 16;
    const int h  = blockIdx.y, b = blockIdx.z;
    const size_t headbase = ((size_t)(b * NH_ + h) * T_SEQ) * (2 * H_DIM);

    {
        const unsigned short* qp = q + headbase + (size_t)q0 * 128;
#pragma unroll
        for (int l = 0; l < 2; l++) {
            int idx = t + 256 * l;
            int row = idx >> 5, w = idx & 31;
            ushort4 uv = *(const ushort4*)(qp + row * 128 + w * 4);
            *(float4*)(&Qs[row * 132 + w * 4]) =
                make_float4(b2f(uv.x), b2f(uv.y), b2f(uv.z), b2f(uv.w));
        }
        if (t < 16) { mrow[t] = -INFINITY; lrow[t] = 0.f; }
    }

    float4 O0 = make_float4(0.f, 0.f, 0.f, 0.f);
    float4 O1 = make_float4(0.f, 0.f, 0.f, 0.f);
    const int orow = t >> 4, oc = t & 15;
    const int sr = t & 15, ss = t >> 4;

    for (int it = 0; it < 32; it++) {
        const int s0 = it * 32;
        __syncthreads();
        const unsigned short* kp = k + headbase + (size_t)s0 * 128;
        const unsigned short* vp = v + headbase + (size_t)s0 * 128;
#pragma unroll
        for (int l = 0; l < 4; l++) {
            int idx = t + 256 * l;
            int row = idx >> 5, w = idx & 31;
            ushort4 ku = *(const ushort4*)(kp + row * 128 + w * 4);
            ushort4 vu = *(const ushort4*)(vp + row * 128 + w * 4);
            *(float4*)(&Ks[row * 132 + w * 4]) =
                make_float4(b2f(ku.x), b2f(ku.y), b2f(ku.z), b2f(ku.w));
            *(float4*)(&Vs[row * 132 + w * 4]) =
                make_float4(b2f(vu.x), b2f(vu.y), b2f(vu.z), b2f(vu.w));
        }
        __syncthreads();

        {
            float re0 = 0.f, im0 = 0.f, re1 = 0.f, im1 = 0.f;
#pragma unroll
            for (int d = 0; d < 64; d++) {
                float2 qv = *(const float2*)(&Qs[sr * 132 + 2 * d]);
                float2 ka = *(const float2*)(&Ks[ss * 132 + 2 * d]);
                float2 kb = *(const float2*)(&Ks[(ss + 16) * 132 + 2 * d]);
                re0 += qv.x * ka.x + qv.y * ka.y;
                im0 += qv.y * ka.x - qv.x * ka.y;
                re1 += qv.x * kb.x + qv.y * kb.y;
                im1 += qv.y * kb.x - qv.x * kb.y;
            }
            S[sr * 33 + ss]      = sqrtf(re0 * re0 + im0 * im0) * 0.125f;
            S[sr * 33 + ss + 16] = sqrtf(re1 * re1 + im1 * im1) * 0.125f;
        }
        __syncthreads();

        if (t < 16) {
            int r = t;
            float mold = mrow[r], mnew = mold;
            for (int s = 0; s < 32; s++) mnew = fmaxf(mnew, S[r * 33 + s]);
            float al = expf(mold - mnew);
            float l2 = lrow[r] * al;
            for (int s = 0; s < 32; s++) {
                float p = expf(S[r * 33 + s] - mnew);
                S[r * 33 + s] = p;
                l2 += p;
            }
            mrow[r] = mnew; lrow[r] = l2; arow[r] = al;
        }
        __syncthreads();

        {
            float al = arow[orow];
            O0.x *= al; O0.y *= al; O0.z *= al; O0.w *= al;
            O1.x *= al; O1.y *= al; O1.z *= al; O1.w *= al;
#pragma unroll 8
            for (int s = 0; s < 32; s++) {
                float p = S[orow * 33 + s];
                float4 v0 = *(const float4*)(&Vs[s * 132 + oc * 4]);
                float4 v1 = *(const float4*)(&Vs[s * 132 + 64 + oc * 4]);
                O0.x += p * v0.x; O0.y += p * v0.y; O0.z += p * v0.z; O0.w += p * v0.w;
                O1.x += p * v1.x; O1.y += p * v1.y; O1.z += p * v1.z; O1.w += p * v1.w;
            }
        }
    }

    {
        float inv = 1.f / lrow[orow];
        int m = b * T_SEQ + q0 + orow;
        int c0 = h * H_DIM + oc * 2;
        size_t base = (size_t)m * C_DIM;
        union { bf16 b2[2]; unsigned int u; } p;
        p.b2[0] = (bf16)(O0.x * inv); p.b2[1] = (bf16)(O0.z * inv);
        *(unsigned int*)&ABr[base + c0] = p.u;
        p.b2[0] = (bf16)(O1.x * inv); p.b2[1] = (bf16)(O1.z * inv);
        *(unsigned int*)&ABr[base + c0 + 32] = p.u;
        p.b2[0] = (bf16)(O0.y * inv); p.b2[1] = (bf16)(O0.w * inv);
        *(unsigned int*)&ABi[base + c0] = p.u;
        p.b2[0] = (bf16)(O1.y * inv); p.b2[1] = (bf16)(O1.w * inv);
        *(unsigned int*)&ABi[base + c0 + 32] = p.u;
    }
}

// ---------------------------------------------------------------------------
extern "C" void kernel_launch(void* const* d_in, const int* in_sizes, int n_in,
                              void* d_out, int out_size, void* d_ws, size_t ws_size,
                              hipStream_t stream) {
    const float* x  = (const float*)d_in[0];
    const float* wq = (const float*)d_in[1];
    const float* bq = (const float*)d_in[2];
    const float* wk = (const float*)d_in[3];
    const float* bk = (const float*)d_in[4];
    const float* wv = (const float*)d_in[5];
    const float* bv = (const float*)d_in[6];
    const float* wo = (const float*)d_in[7];
    const float* bo = (const float*)d_in[8];

    bf16* w = (bf16*)d_ws;
    const size_t MSZ = (size_t)2048 * 1024;   // x / AB plane elems
    const size_t WSZ = (size_t)1024 * 1024;   // weight plane elems
    const size_t HSZ = (size_t)2 * NH_ * T_SEQ * 2 * H_DIM;  // q/k/v buf elems

    bf16 *Xr = w, *Xi = Xr + MSZ;
    bf16 *Wqr = Xi + MSZ,  *Wqi = Wqr + WSZ;
    bf16 *Wkr = Wqi + WSZ, *Wki = Wkr + WSZ;
    bf16 *Wvr = Wki + WSZ, *Wvi = Wvr + WSZ;
    bf16 *Wor = Wvi + WSZ, *Woi = Wor + WSZ;
    bf16 *qb = Woi + WSZ, *kb = qb + HSZ, *vb = kb + HSZ;
    bf16 *ABr = vb + HSZ, *ABi = ABr + MSZ;

    split_complex<<<2048, 256, 0, stream>>>(x,  Xr,  Xi);
    split_complex<<<1024, 256, 0, stream>>>(wq, Wqr, Wqi);
    split_complex<<<1024, 256, 0, stream>>>(wk, Wkr, Wki);
    split_complex<<<1024, 256, 0, stream>>>(wv, Wvr, Wvi);
    split_complex<<<1024, 256, 0, stream>>>(wo, Wor, Woi);

    qkv_gemm<<<dim3(16, 16, 3), 256, 0, stream>>>(
        Xr, Xi, Wqr, Wqi, Wkr, Wki, Wvr, Wvi, bq, bk, bv, qb, kb, vb);

    attn_kernel<<<dim3(T_SEQ / 16, NH_, 2), 256, 0, stream>>>(
        (const unsigned short*)qb, (const unsigned short*)kb,
        (const unsigned short*)vb, ABr, ABi);

    out_gemm<<<dim3(16, 16), 256, 0, stream>>>(ABr, ABi, Wor, Woi, bo, (float*)d_out);
}

// Round 3
// 292.140 us; speedup vs baseline: 13.5939x; 2.9098x over previous
//
#include <hip/hip_runtime.h>
#include <math.h>

#define T_SEQ  1024
#define C_DIM  1024
#define NH_    16
#define H_DIM  64
#define LOG2E  1.4426950408889634f

typedef __bf16 bf16;
typedef __bf16 bf16x4 __attribute__((ext_vector_type(4)));
typedef __bf16 bf16x8 __attribute__((ext_vector_type(8)));
typedef float  f32x4  __attribute__((ext_vector_type(4)));

#define MFMA16(a, b, c) __builtin_amdgcn_mfma_f32_16x16x32_bf16(a, b, c, 0, 0, 0)

#define GLOAD_LDS16(g, l) __builtin_amdgcn_global_load_lds( \
    (const __attribute__((address_space(1))) void*)(g),     \
    (__attribute__((address_space(3))) void*)(l), 16, 0, 0)

__device__ __forceinline__ bf16x8 neg8(bf16x8 x) {
    union { bf16x8 v; unsigned int u[4]; } t;
    t.v = x;
    t.u[0] ^= 0x80008000u; t.u[1] ^= 0x80008000u;
    t.u[2] ^= 0x80008000u; t.u[3] ^= 0x80008000u;
    return t.v;
}

// read a bf16x8 fragment from an XOR-chunk-swizzled [rows][64] bf16 LDS plane
__device__ __forceinline__ bf16x8 frag_sw(const bf16* plane, int row, int chunk) {
    int c = chunk ^ (row & 7);
    return *(const bf16x8*)&plane[row * 64 + c * 8];
}

// ---------------------------------------------------------------------------
// fp32 complex [R][1024][2] -> bf16 planes [R][1024] (re, im)
// ---------------------------------------------------------------------------
__global__ __launch_bounds__(256)
void split_complex(const float* __restrict__ in, bf16* __restrict__ pr,
                   bf16* __restrict__ pi) {
    int idx = (blockIdx.x * 256 + threadIdx.x) * 4;
    float4 v0 = *(const float4*)(in + (size_t)idx * 2);
    float4 v1 = *(const float4*)(in + (size_t)idx * 2 + 4);
    bf16x4 r, im;
    r[0] = (bf16)v0.x; r[1] = (bf16)v0.z; r[2] = (bf16)v1.x; r[3] = (bf16)v1.z;
    im[0] = (bf16)v0.y; im[1] = (bf16)v0.w; im[2] = (bf16)v1.y; im[3] = (bf16)v1.w;
    *(bf16x4*)(pr + idx) = r;
    *(bf16x4*)(pi + idx) = im;
}

// ---------------------------------------------------------------------------
// Complex GEMM core: Y[m][n] = sum_k A[m][k]*B[n][k] + bias[n]  (complex)
// MODE 0: fp32 interleaved [m][1024][2] out (final projection)
// MODE 1: bf16 q/k planes [B,H,T,64] (re,im) with RoPE
// MODE 2: bf16 v planes TRANSPOSED [B,H,64,T] (re,im), no RoPE
// ---------------------------------------------------------------------------
template<int MODE>
__device__ __forceinline__ void cgemm_core(
    const bf16* __restrict__ Ar, const bf16* __restrict__ Ai,
    const bf16* __restrict__ Br, const bf16* __restrict__ Bi,
    const float* __restrict__ bias, float* __restrict__ Yf,
    bf16* __restrict__ Yr, bf16* __restrict__ Yi, int m0, int n0)
{
    __shared__ __attribute__((aligned(16))) bf16 Asr[128 * 32];
    __shared__ __attribute__((aligned(16))) bf16 Asi[128 * 32];
    __shared__ __attribute__((aligned(16))) bf16 Bsr[64 * 32];
    __shared__ __attribute__((aligned(16))) bf16 Bsi[64 * 32];

    const int t = threadIdx.x, lane = t & 63, wave = t >> 6;
    const int wm = (wave >> 1) * 64, wn = (wave & 1) * 32;
    const int lm = lane & 15, quad = lane >> 4;
    const int lr = lane >> 2, lk = (lane & 3) * 8;

    f32x4 accr[4][2], acci[4][2];
#pragma unroll
    for (int i = 0; i < 4; i++)
#pragma unroll
        for (int j = 0; j < 2; j++) { accr[i][j] = (f32x4)0.f; acci[i][j] = (f32x4)0.f; }

    for (int k0 = 0; k0 < C_DIM; k0 += 32) {
#pragma unroll
        for (int j = 0; j < 6; j++) {
            int c = wave + 4 * j;
            const bf16* src; bf16* dst;
            if (c < 8)       { src = Ar + (size_t)(m0 + c * 16 + lr) * C_DIM + k0 + lk;        dst = Asr + c * 512; }
            else if (c < 16) { int cc = c - 8;  src = Ai + (size_t)(m0 + cc * 16 + lr) * C_DIM + k0 + lk; dst = Asi + cc * 512; }
            else if (c < 20) { int cc = c - 16; src = Br + (size_t)(n0 + cc * 16 + lr) * C_DIM + k0 + lk; dst = Bsr + cc * 512; }
            else             { int cc = c - 20; src = Bi + (size_t)(n0 + cc * 16 + lr) * C_DIM + k0 + lk; dst = Bsi + cc * 512; }
            GLOAD_LDS16(src, dst);
        }
        __syncthreads();

        bf16x8 ar[4], ai_[4], br_[2], bi_[2], bn_[2];
#pragma unroll
        for (int i = 0; i < 4; i++) {
            int off = (wm + i * 16 + lm) * 32 + quad * 8;
            ar[i]  = *(const bf16x8*)&Asr[off];
            ai_[i] = *(const bf16x8*)&Asi[off];
        }
#pragma unroll
        for (int j = 0; j < 2; j++) {
            int off = (wn + j * 16 + lm) * 32 + quad * 8;
            br_[j] = *(const bf16x8*)&Bsr[off];
            bi_[j] = *(const bf16x8*)&Bsi[off];
            bn_[j] = neg8(bi_[j]);
        }
#pragma unroll
        for (int i = 0; i < 4; i++)
#pragma unroll
            for (int j = 0; j < 2; j++) {
                accr[i][j] = MFMA16(ar[i],  br_[j], accr[i][j]);
                accr[i][j] = MFMA16(ai_[i], bn_[j], accr[i][j]);
                acci[i][j] = MFMA16(ar[i],  bi_[j], acci[i][j]);
                acci[i][j] = MFMA16(ai_[i], br_[j], acci[i][j]);
            }
        __syncthreads();
    }

    // epilogue — C/D layout: col = lane&15, row = quad*4 + reg
#pragma unroll
    for (int i = 0; i < 4; i++) {
#pragma unroll
        for (int j = 0; j < 2; j++) {
            int n = n0 + wn + j * 16 + lm;
            float2 bv = *(const float2*)&bias[2 * n];
            if (MODE == 2) {
                int t0 = m0 + wm + i * 16 + quad * 4;
                int bb = t0 >> 10, tp0 = t0 & (T_SEQ - 1);
                int hh = n >> 6, d = n & (H_DIM - 1);
                bf16x4 pr, pi2;
#pragma unroll
                for (int r = 0; r < 4; r++) {
                    pr[r]  = (bf16)(accr[i][j][r] + bv.x);
                    pi2[r] = (bf16)(acci[i][j][r] + bv.y);
                }
                size_t o = ((size_t)(bb * NH_ + hh) * H_DIM + d) * T_SEQ + tp0;
                *(bf16x4*)&Yr[o] = pr;
                *(bf16x4*)&Yi[o] = pi2;
            } else {
#pragma unroll
                for (int r = 0; r < 4; r++) {
                    int m = m0 + wm + i * 16 + quad * 4 + r;
                    float yr = accr[i][j][r] + bv.x;
                    float yi = acci[i][j][r] + bv.y;
                    if (MODE == 0) {
                        *(float2*)&Yf[((size_t)m * C_DIM + n) * 2] = make_float2(yr, yi);
                    } else {
                        int tpos = m & (T_SEQ - 1), bb = m >> 10;
                        int hh = n >> 6, d = n & (H_DIM - 1);
                        float invf = exp2f((float)d * -0.2076205059304601f);
                        float fr = (float)tpos * invf;
                        float sn, cs; sincosf(fr, &sn, &cs);
                        float r2 = yr * cs - yi * sn;
                        float i2 = yr * sn + yi * cs;
                        size_t o = ((size_t)(bb * NH_ + hh) * T_SEQ + tpos) * H_DIM + d;
                        Yr[o] = (bf16)r2;
                        Yi[o] = (bf16)i2;
                    }
                }
            }
        }
    }
}

__global__ __launch_bounds__(256, 2)
void qk_gemm(const bf16* __restrict__ Xr, const bf16* __restrict__ Xi,
             const bf16* __restrict__ Wqr, const bf16* __restrict__ Wqi,
             const bf16* __restrict__ Wkr, const bf16* __restrict__ Wki,
             const float* __restrict__ bq, const float* __restrict__ bk,
             bf16* __restrict__ Qr, bf16* __restrict__ Qi,
             bf16* __restrict__ Kr, bf16* __restrict__ Ki)
{
    const bf16 *Br, *Bi; const float* bias; bf16 *Yr, *Yi;
    if (blockIdx.z == 0) { Br = Wqr; Bi = Wqi; bias = bq; Yr = Qr; Yi = Qi; }
    else                 { Br = Wkr; Bi = Wki; bias = bk; Yr = Kr; Yi = Ki; }
    cgemm_core<1>(Xr, Xi, Br, Bi, bias, nullptr, Yr, Yi,
                  blockIdx.y * 128, blockIdx.x * 64);
}

__global__ __launch_bounds__(256, 2)
void v_gemm(const bf16* __restrict__ Xr, const bf16* __restrict__ Xi,
            const bf16* __restrict__ Wvr, const bf16* __restrict__ Wvi,
            const float* __restrict__ bv,
            bf16* __restrict__ Vtr, bf16* __restrict__ Vti)
{
    cgemm_core<2>(Xr, Xi, Wvr, Wvi, bv, nullptr, Vtr, Vti,
                  blockIdx.y * 128, blockIdx.x * 64);
}

__global__ __launch_bounds__(256, 2)
void out_gemm(const bf16* __restrict__ Ar, const bf16* __restrict__ Ai,
              const bf16* __restrict__ Br, const bf16* __restrict__ Bi,
              const float* __restrict__ bias, float* __restrict__ Y)
{
    cgemm_core<0>(Ar, Ai, Br, Bi, bias, Y, nullptr, nullptr,
                  blockIdx.y * 128, blockIdx.x * 64);
}

// ---------------------------------------------------------------------------
// MFMA flash attention. Q/K planes [B,H,T,64] bf16, V planes [B,H,64,T] bf16.
// Block = 64 Q rows (4 waves x 16), K-tile = 64. Output: ABr/ABi [B*T][1024].
// ---------------------------------------------------------------------------
__global__ __launch_bounds__(256, 2)
void attn_mfma(const bf16* __restrict__ Qpr, const bf16* __restrict__ Qpi,
               const bf16* __restrict__ Kpr, const bf16* __restrict__ Kpi,
               const bf16* __restrict__ Vtr, const bf16* __restrict__ Vti,
               bf16* __restrict__ ABr, bf16* __restrict__ ABi)
{
    __shared__ __attribute__((aligned(16))) bf16 Qs_r[4096], Qs_i[4096];
    __shared__ __attribute__((aligned(16))) bf16 Ks_r[4096], Ks_i[4096];
    __shared__ __attribute__((aligned(16))) bf16 Vs_r[4096], Vs_i[4096];
    __shared__ __attribute__((aligned(16))) bf16 Pl[64 * 72];   // stride 72 kills frag-read conflicts

    const int t = threadIdx.x, lane = t & 63, wq = t >> 6;
    const int lm = lane & 15, quad = lane >> 4;
    const int q0 = blockIdx.x * 64;
    const int h = blockIdx.y, b = blockIdx.z;
    const size_t hb = (size_t)(b * NH_ + h) * T_SEQ * H_DIM;

    const int s_lr = lane >> 3;            // row within 8-row staging group
    const int s_c  = (lane & 7) ^ s_lr;    // swizzled source chunk

    // stage Q tile (rows q0..q0+63), swizzled
    {
        const bf16* gq = (wq < 2 ? Qpr : Qpi) + hb + (size_t)q0 * H_DIM;
        bf16* lq = (wq < 2) ? Qs_r : Qs_i;
#pragma unroll
        for (int j = 0; j < 4; j++) {
            int cc = (wq & 1) * 4 + j;
            GLOAD_LDS16(gq + (cc * 8 + s_lr) * H_DIM + s_c * 8, lq + cc * 512);
        }
    }
    __syncthreads();

    bf16x8 qfr[2], qfi[2], nqfr[2];
#pragma unroll
    for (int kh = 0; kh < 2; kh++) {
        qfr[kh]  = frag_sw(Qs_r, wq * 16 + lm, kh * 4 + quad);
        qfi[kh]  = frag_sw(Qs_i, wq * 16 + lm, kh * 4 + quad);
        nqfr[kh] = neg8(qfr[kh]);
    }

    f32x4 Or[4], Oi[4];
#pragma unroll
    for (int nt = 0; nt < 4; nt++) { Or[nt] = (f32x4)0.f; Oi[nt] = (f32x4)0.f; }
    float mold[4] = {0.f, 0.f, 0.f, 0.f}, lsum[4] = {0.f, 0.f, 0.f, 0.f};

    for (int it = 0; it < 16; it++) {
        const int s0 = it * 64;
        __syncthreads();                       // prior-iter K/V readers done
        {
            const bf16* gsrc; bf16* ldst; int gs;
            if (wq == 0)      { gsrc = Kpr + hb + (size_t)s0 * H_DIM; ldst = Ks_r; gs = H_DIM; }
            else if (wq == 1) { gsrc = Kpi + hb + (size_t)s0 * H_DIM; ldst = Ks_i; gs = H_DIM; }
            else if (wq == 2) { gsrc = Vtr + hb + s0;                 ldst = Vs_r; gs = T_SEQ; }
            else              { gsrc = Vti + hb + s0;                 ldst = Vs_i; gs = T_SEQ; }
#pragma unroll
            for (int cc = 0; cc < 8; cc++)
                GLOAD_LDS16(gsrc + (size_t)(cc * 8 + s_lr) * gs + s_c * 8, ldst + cc * 512);
        }
        __syncthreads();

        // ---- scores: 16 q rows x 64 s cols per wave ----
        float sc[4][4];
#pragma unroll
        for (int ct = 0; ct < 4; ct++) {
            f32x4 sre = (f32x4)0.f, sim = (f32x4)0.f;
#pragma unroll
            for (int kh = 0; kh < 2; kh++) {
                bf16x8 kr = frag_sw(Ks_r, ct * 16 + lm, kh * 4 + quad);
                bf16x8 ki = frag_sw(Ks_i, ct * 16 + lm, kh * 4 + quad);
                sre = MFMA16(qfr[kh],  kr, sre);
                sre = MFMA16(qfi[kh],  ki, sre);
                sim = MFMA16(qfi[kh],  kr, sim);
                sim = MFMA16(nqfr[kh], ki, sim);
            }
#pragma unroll
            for (int r = 0; r < 4; r++)
                sc[ct][r] = sqrtf(sre[r] * sre[r] + sim[r] * sim[r]) * 0.125f;
        }

        // ---- online softmax (rows = quad*4+r, cols across 16-lane group) ----
        float mx[4], mnew[4], alpha[4], ps[4];
#pragma unroll
        for (int r = 0; r < 4; r++)
            mx[r] = fmaxf(fmaxf(sc[0][r], sc[1][r]), fmaxf(sc[2][r], sc[3][r]));
#pragma unroll
        for (int msk = 1; msk < 16; msk <<= 1)
#pragma unroll
            for (int r = 0; r < 4; r++) mx[r] = fmaxf(mx[r], __shfl_xor(mx[r], msk));
#pragma unroll
        for (int r = 0; r < 4; r++) {
            mnew[r]  = fmaxf(mold[r], mx[r]);
            alpha[r] = exp2f((mold[r] - mnew[r]) * LOG2E);
            ps[r] = 0.f;
        }
#pragma unroll
        for (int ct = 0; ct < 4; ct++)
#pragma unroll
            for (int r = 0; r < 4; r++) {
                float p = exp2f((sc[ct][r] - mnew[r]) * LOG2E);
                ps[r] += p;
                Pl[(wq * 16 + quad * 4 + r) * 72 + ct * 16 + lm] = (bf16)p;
            }
#pragma unroll
        for (int msk = 1; msk < 16; msk <<= 1)
#pragma unroll
            for (int r = 0; r < 4; r++) ps[r] += __shfl_xor(ps[r], msk);
#pragma unroll
        for (int r = 0; r < 4; r++) {
            lsum[r] = lsum[r] * alpha[r] + ps[r];
            mold[r] = mnew[r];
        }
#pragma unroll
        for (int nt = 0; nt < 4; nt++)
#pragma unroll
            for (int r = 0; r < 4; r++) { Or[nt][r] *= alpha[r]; Oi[nt][r] *= alpha[r]; }

        // ---- PV: O[16 q x 64 d] += P[16 x 64] @ V[64 s x 64 d] ----
        bf16x8 pf[2];
#pragma unroll
        for (int kh = 0; kh < 2; kh++)
            pf[kh] = *(const bf16x8*)&Pl[(wq * 16 + lm) * 72 + kh * 32 + quad * 8];
#pragma unroll
        for (int nt = 0; nt < 4; nt++)
#pragma unroll
            for (int kh = 0; kh < 2; kh++) {
                Or[nt] = MFMA16(pf[kh], frag_sw(Vs_r, nt * 16 + lm, kh * 4 + quad), Or[nt]);
                Oi[nt] = MFMA16(pf[kh], frag_sw(Vs_i, nt * 16 + lm, kh * 4 + quad), Oi[nt]);
            }
    }

    // epilogue
    float linv[4];
#pragma unroll
    for (int r = 0; r < 4; r++) linv[r] = 1.f / lsum[r];
    size_t mbase = (size_t)(b * T_SEQ + q0 + wq * 16 + quad * 4) * C_DIM;
    int colb = h * H_DIM + lm;
#pragma unroll
    for (int nt = 0; nt < 4; nt++)
#pragma unroll
        for (int r = 0; r < 4; r++) {
            size_t o = mbase + (size_t)r * C_DIM + colb + nt * 16;
            ABr[o] = (bf16)(Or[nt][r] * linv[r]);
            ABi[o] = (bf16)(Oi[nt][r] * linv[r]);
        }
}

// ---------------------------------------------------------------------------
extern "C" void kernel_launch(void* const* d_in, const int* in_sizes, int n_in,
                              void* d_out, int out_size, void* d_ws, size_t ws_size,
                              hipStream_t stream) {
    const float* x  = (const float*)d_in[0];
    const float* wq = (const float*)d_in[1];
    const float* bq = (const float*)d_in[2];
    const float* wk = (const float*)d_in[3];
    const float* bk = (const float*)d_in[4];
    const float* wv = (const float*)d_in[5];
    const float* bv = (const float*)d_in[6];
    const float* wo = (const float*)d_in[7];
    const float* bo = (const float*)d_in[8];

    bf16* w = (bf16*)d_ws;
    const size_t MSZ = (size_t)2048 * 1024;                 // x / AB plane elems
    const size_t WSZ = (size_t)1024 * 1024;                 // weight plane elems
    const size_t PSZ = (size_t)2 * NH_ * T_SEQ * H_DIM;     // q/k/v plane elems

    bf16 *Xr = w, *Xi = Xr + MSZ;
    bf16 *Wqr = Xi + MSZ,  *Wqi = Wqr + WSZ;
    bf16 *Wkr = Wqi + WSZ, *Wki = Wkr + WSZ;
    bf16 *Wvr = Wki + WSZ, *Wvi = Wvr + WSZ;
    bf16 *Wor = Wvi + WSZ, *Woi = Wor + WSZ;
    bf16 *Qr = Woi + WSZ, *Qi = Qr + PSZ;
    bf16 *Kr = Qi + PSZ,  *Ki = Kr + PSZ;
    bf16 *Vr = Ki + PSZ,  *Vi = Vr + PSZ;
    bf16 *ABr = Vi + PSZ, *ABi = ABr + MSZ;

    split_complex<<<2048, 256, 0, stream>>>(x,  Xr,  Xi);
    split_complex<<<1024, 256, 0, stream>>>(wq, Wqr, Wqi);
    split_complex<<<1024, 256, 0, stream>>>(wk, Wkr, Wki);
    split_complex<<<1024, 256, 0, stream>>>(wv, Wvr, Wvi);
    split_complex<<<1024, 256, 0, stream>>>(wo, Wor, Woi);

    qk_gemm<<<dim3(16, 16, 2), 256, 0, stream>>>(
        Xr, Xi, Wqr, Wqi, Wkr, Wki, bq, bk, Qr, Qi, Kr, Ki);
    v_gemm<<<dim3(16, 16), 256, 0, stream>>>(Xr, Xi, Wvr, Wvi, bv, Vr, Vi);

    attn_mfma<<<dim3(T_SEQ / 64, NH_, 2), 256, 0, stream>>>(
        Qr, Qi, Kr, Ki, Vr, Vi, ABr, ABi);

    out_gemm<<<dim3(16, 16), 256, 0, stream>>>(ABr, ABi, Wor, Woi, bo, (float*)d_out);
}

// Round 4
// 249.589 us; speedup vs baseline: 15.9115x; 1.1705x over previous
//
#include <hip/hip_runtime.h>
#include <math.h>

#define T_SEQ  1024
#define C_DIM  1024
#define NH_    16
#define H_DIM  64
#define SCL    (0.125f * 1.4426950408889634f)   // 1/sqrt(64) folded with log2e

typedef __bf16 bf16;
typedef __bf16 bf16x4 __attribute__((ext_vector_type(4)));
typedef __bf16 bf16x8 __attribute__((ext_vector_type(8)));
typedef float  f32x4  __attribute__((ext_vector_type(4)));

#define MFMA16(a, b, c) __builtin_amdgcn_mfma_f32_16x16x32_bf16(a, b, c, 0, 0, 0)

#define GLOAD_LDS16(g, l) __builtin_amdgcn_global_load_lds( \
    (const __attribute__((address_space(1))) void*)(g),     \
    (__attribute__((address_space(3))) void*)(l), 16, 0, 0)

__device__ __forceinline__ bf16x8 neg8(bf16x8 x) {
    union { bf16x8 v; unsigned int u[4]; } t;
    t.v = x;
    t.u[0] ^= 0x80008000u; t.u[1] ^= 0x80008000u;
    t.u[2] ^= 0x80008000u; t.u[3] ^= 0x80008000u;
    return t.v;
}

// fragment read from XOR-8-chunk-swizzled [rows][64] plane
__device__ __forceinline__ bf16x8 frag_sw(const bf16* plane, int row, int chunk) {
    int c = chunk ^ (row & 7);
    return *(const bf16x8*)&plane[row * 64 + c * 8];
}
// fragment read from XOR-4-chunk-swizzled [rows][32] plane
__device__ __forceinline__ bf16x8 frag_sw4(const bf16* plane, int row, int chunk) {
    int c = chunk ^ (row & 3);
    return *(const bf16x8*)&plane[row * 32 + c * 8];
}

// ---------------------------------------------------------------------------
// splits: fp32 complex [R][1024][2] -> bf16 planes (re, im). z picks source.
// ---------------------------------------------------------------------------
__global__ __launch_bounds__(256)
void split_all(const float* __restrict__ x,  const float* __restrict__ wq,
               const float* __restrict__ wk, const float* __restrict__ wv,
               const float* __restrict__ wo,
               bf16* Xr, bf16* Xi, bf16* Wqr, bf16* Wqi, bf16* Wkr, bf16* Wki,
               bf16* Wvr, bf16* Wvi, bf16* Wor, bf16* Woi)
{
    int z = blockIdx.y;
    if (z > 0 && blockIdx.x >= 1024) return;
    const float* in; bf16 *pr, *pi;
    if      (z == 0) { in = x;  pr = Xr;  pi = Xi;  }
    else if (z == 1) { in = wq; pr = Wqr; pi = Wqi; }
    else if (z == 2) { in = wk; pr = Wkr; pi = Wki; }
    else if (z == 3) { in = wv; pr = Wvr; pi = Wvi; }
    else             { in = wo; pr = Wor; pi = Woi; }
    int idx = (blockIdx.x * 256 + threadIdx.x) * 4;
    float4 v0 = *(const float4*)(in + (size_t)idx * 2);
    float4 v1 = *(const float4*)(in + (size_t)idx * 2 + 4);
    bf16x4 r, im;
    r[0] = (bf16)v0.x; r[1] = (bf16)v0.z; r[2] = (bf16)v1.x; r[3] = (bf16)v1.z;
    im[0] = (bf16)v0.y; im[1] = (bf16)v0.w; im[2] = (bf16)v1.y; im[3] = (bf16)v1.w;
    *(bf16x4*)(pr + idx) = r;
    *(bf16x4*)(pi + idx) = im;
}

// RoPE phasor table: rope[t*64+d] = (cos, sin)
__global__ __launch_bounds__(256)
void rope_init(float* __restrict__ rope) {
    int idx = blockIdx.x * 256 + threadIdx.x;   // 65536
    int tp = idx >> 6, d = idx & 63;
    float invf = exp2f((float)d * -0.2076205059304601f);
    float fr = (float)tp * invf;
    float sn, cs; sincosf(fr, &sn, &cs);
    *(float2*)&rope[(size_t)idx * 2] = make_float2(cs, sn);
}

// ---------------------------------------------------------------------------
// 128x64 complex GEMM core. MODE 1: q/k planes [B,H,T,64] + RoPE.
// MODE 2: v planes transposed [B,H,64,T]. LDS-transpose vectorized epilogues.
// ---------------------------------------------------------------------------
template<int MODE>
__device__ __forceinline__ void cgemm128(
    const bf16* __restrict__ Ar, const bf16* __restrict__ Ai,
    const bf16* __restrict__ Br, const bf16* __restrict__ Bi,
    const float* __restrict__ bias, const float* __restrict__ rope,
    bf16* __restrict__ Yr, bf16* __restrict__ Yi, int m0, int n0)
{
    __shared__ __attribute__((aligned(16))) bf16 smem[12288];  // 24 KB
    const int t = threadIdx.x, lane = t & 63, wave = t >> 6;
    const int wm = (wave >> 1) * 64, wn = (wave & 1) * 32;
    const int lm = lane & 15, quad = lane >> 4;
    const int lr = lane >> 2;
    const int sc4 = ((lane & 3) ^ (lr & 3)) * 8;   // swizzled k-chunk

    f32x4 accr[4][2], acci[4][2];
#pragma unroll
    for (int i = 0; i < 4; i++)
#pragma unroll
        for (int j = 0; j < 2; j++) { accr[i][j] = (f32x4)0.f; acci[i][j] = (f32x4)0.f; }

    for (int k0 = 0; k0 < C_DIM; k0 += 32) {
#pragma unroll
        for (int j = 0; j < 6; j++) {
            int c = wave + 4 * j;
            const bf16* src; bf16* dst;
            if (c < 8)       { src = Ar + (size_t)(m0 + c * 16 + lr) * C_DIM + k0 + sc4;        dst = smem + c * 512; }
            else if (c < 16) { int cc = c - 8;  src = Ai + (size_t)(m0 + cc * 16 + lr) * C_DIM + k0 + sc4; dst = smem + 4096 + cc * 512; }
            else if (c < 20) { int cc = c - 16; src = Br + (size_t)(n0 + cc * 16 + lr) * C_DIM + k0 + sc4; dst = smem + 8192 + cc * 512; }
            else             { int cc = c - 20; src = Bi + (size_t)(n0 + cc * 16 + lr) * C_DIM + k0 + sc4; dst = smem + 10240 + cc * 512; }
            GLOAD_LDS16(src, dst);
        }
        __syncthreads();

        bf16x8 ar[4], ai_[4], br_[2], bi_[2], bn_[2];
#pragma unroll
        for (int i = 0; i < 4; i++) {
            ar[i]  = frag_sw4(smem,        wm + i * 16 + lm, quad);
            ai_[i] = frag_sw4(smem + 4096, wm + i * 16 + lm, quad);
        }
#pragma unroll
        for (int j = 0; j < 2; j++) {
            br_[j] = frag_sw4(smem + 8192,  wn + j * 16 + lm, quad);
            bi_[j] = frag_sw4(smem + 10240, wn + j * 16 + lm, quad);
            bn_[j] = neg8(bi_[j]);
        }
#pragma unroll
        for (int i = 0; i < 4; i++)
#pragma unroll
            for (int j = 0; j < 2; j++) {
                accr[i][j] = MFMA16(ar[i],  br_[j], accr[i][j]);
                accr[i][j] = MFMA16(ai_[i], bn_[j], accr[i][j]);
                acci[i][j] = MFMA16(ar[i],  bi_[j], acci[i][j]);
                acci[i][j] = MFMA16(ai_[i], br_[j], acci[i][j]);
            }
        __syncthreads();
    }

    const int h = n0 >> 6, bb = m0 >> 10, tbase = m0 & (T_SEQ - 1);

    if (MODE == 1) {
        // bias + RoPE rotate in place (table lookup)
#pragma unroll
        for (int i = 0; i < 4; i++)
#pragma unroll
            for (int j = 0; j < 2; j++) {
                int d = wn + j * 16 + lm;
                float2 bv = *(const float2*)&bias[2 * (n0 + d)];
#pragma unroll
                for (int r = 0; r < 4; r++) {
                    int tpos = tbase + wm + i * 16 + quad * 4 + r;
                    float2 ph = *(const float2*)&rope[((size_t)tpos * H_DIM + d) * 2];
                    float yr = accr[i][j][r] + bv.x;
                    float yi = acci[i][j][r] + bv.y;
                    accr[i][j][r] = yr * ph.x - yi * ph.y;
                    acci[i][j][r] = yr * ph.y + yi * ph.x;
                }
            }
        // two-pass LDS transpose -> b128 stores, planes [B,H,T,64]
        bf16* dsts[2] = { Yr, Yi };
#pragma unroll
        for (int pass = 0; pass < 2; pass++) {
            __syncthreads();
#pragma unroll
            for (int i = 0; i < 4; i++)
#pragma unroll
                for (int j = 0; j < 2; j++)
#pragma unroll
                    for (int r = 0; r < 4; r++)
                        smem[(wm + i * 16 + quad * 4 + r) * 72 + wn + j * 16 + lm] =
                            (bf16)(pass ? acci[i][j][r] : accr[i][j][r]);
            __syncthreads();
            bf16* dst = dsts[pass] + ((size_t)(bb * NH_ + h) * T_SEQ + tbase) * H_DIM;
#pragma unroll
            for (int p = 0; p < 4; p++) {
                int ch = t + 256 * p;
                int row = ch >> 3, o = (ch & 7) * 8;
                *(bf16x8*)&dst[row * H_DIM + o] = *(const bf16x8*)&smem[row * 72 + o];
            }
        }
    } else {
        // V: two-pass LDS transpose to [d][t] -> b128 stores, planes [B,H,64,T]
        bf16* dsts[2] = { Yr, Yi };
#pragma unroll
        for (int pass = 0; pass < 2; pass++) {
            __syncthreads();
#pragma unroll
            for (int i = 0; i < 4; i++)
#pragma unroll
                for (int j = 0; j < 2; j++) {
                    int d = wn + j * 16 + lm;
                    float2 bv = *(const float2*)&bias[2 * (n0 + d)];
                    float bb2 = pass ? bv.y : bv.x;
                    bf16x4 pk;
#pragma unroll
                    for (int r = 0; r < 4; r++)
                        pk[r] = (bf16)((pass ? acci[i][j][r] : accr[i][j][r]) + bb2);
                    *(bf16x4*)&smem[d * 136 + wm + i * 16 + quad * 4] = pk;
                }
            __syncthreads();
            bf16* dst = dsts[pass] + ((size_t)(bb * NH_ + h) * H_DIM) * T_SEQ + tbase;
#pragma unroll
            for (int p = 0; p < 4; p++) {
                int ch = t + 256 * p;
                int row = ch >> 4, o = (ch & 15) * 8;
                *(bf16x8*)&dst[(size_t)row * T_SEQ + o] = *(const bf16x8*)&smem[row * 136 + o];
            }
        }
    }
}

__global__ __launch_bounds__(256, 3)
void qkv_gemm(const bf16* __restrict__ Xr, const bf16* __restrict__ Xi,
              const bf16* __restrict__ Wqr, const bf16* __restrict__ Wqi,
              const bf16* __restrict__ Wkr, const bf16* __restrict__ Wki,
              const bf16* __restrict__ Wvr, const bf16* __restrict__ Wvi,
              const float* __restrict__ bq, const float* __restrict__ bk,
              const float* __restrict__ bv, const float* __restrict__ rope,
              bf16* Qr, bf16* Qi, bf16* Kr, bf16* Ki, bf16* Vr, bf16* Vi)
{
    int m0 = blockIdx.y * 128, n0 = blockIdx.x * 64;
    if (blockIdx.z == 0)      cgemm128<1>(Xr, Xi, Wqr, Wqi, bq, rope, Qr, Qi, m0, n0);
    else if (blockIdx.z == 1) cgemm128<1>(Xr, Xi, Wkr, Wki, bk, rope, Kr, Ki, m0, n0);
    else                      cgemm128<2>(Xr, Xi, Wvr, Wvi, bv, nullptr, Vr, Vi, m0, n0);
}

// ---------------------------------------------------------------------------
// 64x64 complex GEMM (final projection, fp32 interleaved out). 512 blocks.
// ---------------------------------------------------------------------------
__global__ __launch_bounds__(256, 2)
void out_gemm(const bf16* __restrict__ Ar, const bf16* __restrict__ Ai,
              const bf16* __restrict__ Br, const bf16* __restrict__ Bi,
              const float* __restrict__ bias, float* __restrict__ Y)
{
    __shared__ __attribute__((aligned(16))) bf16 sm[8192];   // 16 KB
    const int t = threadIdx.x, lane = t & 63, wave = t >> 6;
    const int lm = lane & 15, quad = lane >> 4;
    const int lr = lane >> 2;
    const int sc4 = ((lane & 3) ^ (lr & 3)) * 8;
    const int wm = (wave >> 1) * 32, wn = (wave & 1) * 32;
    const int m0 = blockIdx.y * 64, n0 = blockIdx.x * 64;

    f32x4 accr[2][2], acci[2][2];
#pragma unroll
    for (int i = 0; i < 2; i++)
#pragma unroll
        for (int j = 0; j < 2; j++) { accr[i][j] = (f32x4)0.f; acci[i][j] = (f32x4)0.f; }

    for (int k0 = 0; k0 < C_DIM; k0 += 32) {
#pragma unroll
        for (int j = 0; j < 4; j++) {
            int c = wave + 4 * j;
            const bf16* src; bf16* dst;
            if (c < 4)       { src = Ar + (size_t)(m0 + c * 16 + lr) * C_DIM + k0 + sc4;        dst = sm + c * 512; }
            else if (c < 8)  { int cc = c - 4;  src = Ai + (size_t)(m0 + cc * 16 + lr) * C_DIM + k0 + sc4; dst = sm + 2048 + cc * 512; }
            else if (c < 12) { int cc = c - 8;  src = Br + (size_t)(n0 + cc * 16 + lr) * C_DIM + k0 + sc4; dst = sm + 4096 + cc * 512; }
            else             { int cc = c - 12; src = Bi + (size_t)(n0 + cc * 16 + lr) * C_DIM + k0 + sc4; dst = sm + 6144 + cc * 512; }
            GLOAD_LDS16(src, dst);
        }
        __syncthreads();
        bf16x8 ar[2], ai_[2], br_[2], bi_[2], bn_[2];
#pragma unroll
        for (int i = 0; i < 2; i++) {
            ar[i]  = frag_sw4(sm,        wm + i * 16 + lm, quad);
            ai_[i] = frag_sw4(sm + 2048, wm + i * 16 + lm, quad);
        }
#pragma unroll
        for (int j = 0; j < 2; j++) {
            br_[j] = frag_sw4(sm + 4096, wn + j * 16 + lm, quad);
            bi_[j] = frag_sw4(sm + 6144, wn + j * 16 + lm, quad);
            bn_[j] = neg8(bi_[j]);
        }
#pragma unroll
        for (int i = 0; i < 2; i++)
#pragma unroll
            for (int j = 0; j < 2; j++) {
                accr[i][j] = MFMA16(ar[i],  br_[j], accr[i][j]);
                accr[i][j] = MFMA16(ai_[i], bn_[j], accr[i][j]);
                acci[i][j] = MFMA16(ar[i],  bi_[j], acci[i][j]);
                acci[i][j] = MFMA16(ai_[i], br_[j], acci[i][j]);
            }
        __syncthreads();
    }
#pragma unroll
    for (int i = 0; i < 2; i++)
#pragma unroll
        for (int j = 0; j < 2; j++) {
            int n = n0 + wn + j * 16 + lm;
            float2 bv = *(const float2*)&bias[2 * n];
#pragma unroll
            for (int r = 0; r < 4; r++) {
                int m = m0 + wm + i * 16 + quad * 4 + r;
                *(float2*)&Y[((size_t)m * C_DIM + n) * 2] =
                    make_float2(accr[i][j][r] + bv.x, acci[i][j][r] + bv.y);
            }
        }
}

// ---------------------------------------------------------------------------
// MFMA flash attention, S^T layout, 8 waves (2 s-halves x 4 q-groups).
// Q/K planes [B,H,T,64], V planes [B,H,64,T]. Out: ABr/ABi [B*T][1024].
// LDS 48 KB: [Q 16K | sh0: Kr,Ki,Vr,Vi 4K each | sh1: same]. K-tile = 32.
// ---------------------------------------------------------------------------
__global__ __launch_bounds__(512, 4)
void attn_mfma(const bf16* __restrict__ Qpr, const bf16* __restrict__ Qpi,
               const bf16* __restrict__ Kpr, const bf16* __restrict__ Kpi,
               const bf16* __restrict__ Vtr, const bf16* __restrict__ Vti,
               bf16* __restrict__ ABr, bf16* __restrict__ ABi)
{
    __shared__ __attribute__((aligned(16))) bf16 smem[24576];  // 48 KB
    const int t = threadIdx.x, lane = t & 63, w = t >> 6;
    const int qg = w & 3, sh = w >> 2;
    const int lm = lane & 15, quad = lane >> 4;
    const int q0 = blockIdx.x * 64;
    const int h = blockIdx.y, b = blockIdx.z;
    const size_t hb = (size_t)(b * NH_ + h) * T_SEQ * H_DIM;
    const int s_lr = lane >> 3, s_c = (lane & 7) ^ s_lr;        // 8-chunk swizzle
    const int lr4 = lane >> 2, sc4 = ((lane & 3) ^ (lr4 & 3)) * 8;  // 4-chunk swizzle

    // stage Q (64 rows x 64), 16 chunks over 8 waves
    {
        const bf16* gq = (sh == 0 ? Qpr : Qpi) + hb + (size_t)q0 * H_DIM;
        bf16* lq = smem + sh * 4096;
#pragma unroll
        for (int j = 0; j < 2; j++) {
            int cc = qg * 2 + j;
            GLOAD_LDS16(gq + (cc * 8 + s_lr) * H_DIM + s_c * 8, lq + cc * 512);
        }
    }
    __syncthreads();

    bf16x8 qfr[2], qfi[2], nqfr[2];
#pragma unroll
    for (int kh = 0; kh < 2; kh++) {
        qfr[kh]  = frag_sw(smem,        qg * 16 + lm, kh * 4 + quad);
        qfi[kh]  = frag_sw(smem + 4096, qg * 16 + lm, kh * 4 + quad);
        nqfr[kh] = neg8(qfr[kh]);
    }

    bf16* Ks_r = smem + 8192 + sh * 8192;
    bf16* Ks_i = Ks_r + 2048;
    bf16* Vs_r = Ks_r + 4096;
    bf16* Vs_i = Ks_r + 6144;
    bf16* Pl   = smem;                     // 128 rows x 32, swizzled (aliases Q)
    const int prow = sh * 64 + qg * 16 + lm;

    f32x4 Or[4], Oi[4];
#pragma unroll
    for (int nt = 0; nt < 4; nt++) { Or[nt] = (f32x4)0.f; Oi[nt] = (f32x4)0.f; }
    float mold = 0.f, lsum = 0.f;

    for (int it = 0; it < 16; it++) {
        const int s0 = it * 32 + sh * 512;
        __syncthreads();
        {   // wave (qg, sh) stages plane qg of its s-half: 4 chunks
            if (qg < 2) {
                const bf16* gsrc = (qg == 0 ? Kpr : Kpi) + hb + (size_t)s0 * H_DIM;
                bf16* ldst = (qg == 0) ? Ks_r : Ks_i;
#pragma unroll
                for (int cc = 0; cc < 4; cc++)
                    GLOAD_LDS16(gsrc + (cc * 8 + s_lr) * H_DIM + s_c * 8, ldst + cc * 512);
            } else {
                const bf16* gsrc = (qg == 2 ? Vtr : Vti) + hb + s0;
                bf16* ldst = (qg == 2) ? Vs_r : Vs_i;
#pragma unroll
                for (int cc = 0; cc < 4; cc++)
                    GLOAD_LDS16(gsrc + (size_t)(cc * 16 + lr4) * T_SEQ + sc4, ldst + cc * 512);
            }
        }
        __syncthreads();

        // S^T scores: A = K frags (m = s), B = Q frags (n = q)
        float sc[2][4];
#pragma unroll
        for (int ct = 0; ct < 2; ct++) {
            f32x4 sre = (f32x4)0.f, sim = (f32x4)0.f;
#pragma unroll
            for (int kh = 0; kh < 2; kh++) {
                bf16x8 kr = frag_sw(Ks_r, ct * 16 + lm, kh * 4 + quad);
                bf16x8 ki = frag_sw(Ks_i, ct * 16 + lm, kh * 4 + quad);
                sre = MFMA16(kr, qfr[kh],  sre);
                sre = MFMA16(ki, qfi[kh],  sre);
                sim = MFMA16(kr, qfi[kh],  sim);
                sim = MFMA16(ki, nqfr[kh], sim);
            }
#pragma unroll
            for (int r = 0; r < 4; r++)
                sc[ct][r] = sqrtf(sre[r] * sre[r] + sim[r] * sim[r]) * SCL;
        }

        // online softmax, state per lane (q = lm), reduce across quads
        float mx = sc[0][0];
#pragma unroll
        for (int ct = 0; ct < 2; ct++)
#pragma unroll
            for (int r = 0; r < 4; r++) mx = fmaxf(mx, sc[ct][r]);
        mx = fmaxf(mx, __shfl_xor(mx, 16));
        mx = fmaxf(mx, __shfl_xor(mx, 32));
        float mnew = fmaxf(mold, mx);
        float alpha = exp2f(mold - mnew);
        float ps = 0.f;
#pragma unroll
        for (int ct = 0; ct < 2; ct++) {
            bf16x4 pk;
#pragma unroll
            for (int r = 0; r < 4; r++) {
                float p = exp2f(sc[ct][r] - mnew);
                ps += p;
                pk[r] = (bf16)p;
            }
            *(bf16x4*)&Pl[prow * 32 + ((ct * 2 + (quad >> 1)) ^ (prow & 3)) * 8
                          + (quad & 1) * 4] = pk;
        }
        ps += __shfl_xor(ps, 16);
        ps += __shfl_xor(ps, 32);
        lsum = lsum * alpha + ps;
        mold = mnew;

        float aO[4];
#pragma unroll
        for (int r = 0; r < 4; r++)
            aO[r] = __shfl(alpha, (quad << 4) + quad * 4 + r, 64);
#pragma unroll
        for (int nt = 0; nt < 4; nt++)
#pragma unroll
            for (int r = 0; r < 4; r++) { Or[nt][r] *= aO[r]; Oi[nt][r] *= aO[r]; }

        // PV: A = P (m = q, from regs via Pl), B = V^T frags
        bf16x8 pf = frag_sw4(Pl, prow, quad);
#pragma unroll
        for (int nt = 0; nt < 4; nt++) {
            Or[nt] = MFMA16(pf, frag_sw4(Vs_r, nt * 16 + lm, quad), Or[nt]);
            Oi[nt] = MFMA16(pf, frag_sw4(Vs_i, nt * 16 + lm, quad), Oi[nt]);
        }
    }

    // merge s-halves: sh1 -> LDS, sh0 combines and writes out
    float* Of = (float*)(smem + 8192);   // 32 KB at byte 16384 (staging region)
    float* ml = (float*)smem;            // Pl region, dead
    __syncthreads();
    if (sh == 1) {
#pragma unroll
        for (int nt = 0; nt < 4; nt++)
#pragma unroll
            for (int r = 0; r < 4; r++) {
                Of[((qg * 2 + 0) * 16 + quad * 4 + r) * 64 + nt * 16 + lm] = Or[nt][r];
                Of[((qg * 2 + 1) * 16 + quad * 4 + r) * 64 + nt * 16 + lm] = Oi[nt][r];
            }
        if (quad == 0) *(float2*)&ml[(qg * 16 + lm) * 2] = make_float2(mold, lsum);
    }
    __syncthreads();
    if (sh == 0) {
        float2 m2 = *(const float2*)&ml[(qg * 16 + lm) * 2];
        float mn = fmaxf(mold, m2.x);
        float a1 = exp2f(mold - mn), a2 = exp2f(m2.x - mn);
        lsum = a1 * lsum + a2 * m2.y;
        float a1r[4], a2r[4], linv[4];
        float lv = 1.f / lsum;
#pragma unroll
        for (int r = 0; r < 4; r++) {
            int src = (quad << 4) + quad * 4 + r;
            a1r[r]  = __shfl(a1, src, 64);
            a2r[r]  = __shfl(a2, src, 64);
            linv[r] = __shfl(lv, src, 64);
        }
        size_t mbase = (size_t)(b * T_SEQ + q0 + qg * 16 + quad * 4) * C_DIM;
        int colb = h * H_DIM + lm;
#pragma unroll
        for (int nt = 0; nt < 4; nt++)
#pragma unroll
            for (int r = 0; r < 4; r++) {
                float orv = a1r[r] * Or[nt][r] +
                            a2r[r] * Of[((qg * 2 + 0) * 16 + quad * 4 + r) * 64 + nt * 16 + lm];
                float oiv = a1r[r] * Oi[nt][r] +
                            a2r[r] * Of[((qg * 2 + 1) * 16 + quad * 4 + r) * 64 + nt * 16 + lm];
                size_t o = mbase + (size_t)r * C_DIM + colb + nt * 16;
                ABr[o] = (bf16)(orv * linv[r]);
                ABi[o] = (bf16)(oiv * linv[r]);
            }
    }
}

// ---------------------------------------------------------------------------
extern "C" void kernel_launch(void* const* d_in, const int* in_sizes, int n_in,
                              void* d_out, int out_size, void* d_ws, size_t ws_size,
                              hipStream_t stream) {
    const float* x  = (const float*)d_in[0];
    const float* wq = (const float*)d_in[1];
    const float* bq = (const float*)d_in[2];
    const float* wk = (const float*)d_in[3];
    const float* bk = (const float*)d_in[4];
    const float* wv = (const float*)d_in[5];
    const float* bv = (const float*)d_in[6];
    const float* wo = (const float*)d_in[7];
    const float* bo = (const float*)d_in[8];

    float* rope = (float*)d_ws;                       // 131072 floats (512 KB)
    bf16* w = (bf16*)(rope + 131072);
    const size_t MSZ = (size_t)2048 * 1024;
    const size_t WSZ = (size_t)1024 * 1024;
    const size_t PSZ = (size_t)2 * NH_ * T_SEQ * H_DIM;

    bf16 *Xr = w, *Xi = Xr + MSZ;
    bf16 *Wqr = Xi + MSZ,  *Wqi = Wqr + WSZ;
    bf16 *Wkr = Wqi + WSZ, *Wki = Wkr + WSZ;
    bf16 *Wvr = Wki + WSZ, *Wvi = Wvr + WSZ;
    bf16 *Wor = Wvi + WSZ, *Woi = Wor + WSZ;
    bf16 *Qr = Woi + WSZ, *Qi = Qr + PSZ;
    bf16 *Kr = Qi + PSZ,  *Ki = Kr + PSZ;
    bf16 *Vr = Ki + PSZ,  *Vi = Vr + PSZ;
    bf16 *ABr = Vi + PSZ, *ABi = ABr + MSZ;

    split_all<<<dim3(2048, 5), 256, 0, stream>>>(x, wq, wk, wv, wo,
        Xr, Xi, Wqr, Wqi, Wkr, Wki, Wvr, Wvi, Wor, Woi);
    rope_init<<<256, 256, 0, stream>>>(rope);

    qkv_gemm<<<dim3(16, 16, 3), 256, 0, stream>>>(
        Xr, Xi, Wqr, Wqi, Wkr, Wki, Wvr, Wvi, bq, bk, bv, rope,
        Qr, Qi, Kr, Ki, Vr, Vi);

    attn_mfma<<<dim3(16, 16, 2), 512, 0, stream>>>(
        Qr, Qi, Kr, Ki, Vr, Vi, ABr, ABi);

    out_gemm<<<dim3(16, 32), 256, 0, stream>>>(ABr, ABi, Wor, Woi, bo, (float*)d_out);
}